// Round 1
// baseline (26.703 us; speedup 1.0000x reference)
//
#include <hip/hip_runtime.h>

// 7x7 median blur, zero padding, on (image+1)/2, then *2-1, clip [-1,1].
// Strategy: clamp to [0,1] (monotone, commutes with median+clip), quantize to
// 7 bits (error bound 1/127 = 7.9e-3 << 2e-2 threshold), maintain per-thread
// rolling 49-bit bit-plane masks down a column run, MSB-first radix select
// rank 24 via popcount.

#define IMG_H 256
#define IMG_W 256
#define RROWS 16                 // output rows per thread run
#define RUNS  (IMG_H / RROWS)    // 16

__global__ __launch_bounds__(256)
void median7_kernel(const float* __restrict__ img, float* __restrict__ out) {
    const int x     = threadIdx.x;              // column 0..255
    const int plane = blockIdx.x / RUNS;        // b*c plane
    const int run   = blockIdx.x % RUNS;
    const int y0    = run * RROWS;

    const float* ip = img + (size_t)plane * (IMG_H * IMG_W);
    float*       op = out + (size_t)plane * (IMG_H * IMG_W);

    // Per-column tap validity (zero padding in [0,1] domain -> quantized 0)
    float cm[7];
    int   cc[7];
#pragma unroll
    for (int dx = 0; dx < 7; ++dx) {
        int col = x + dx - 3;
        cm[dx] = (col >= 0 && col < IMG_W) ? 1.0f : 0.0f;
        cc[dx] = min(max(col, 0), IMG_W - 1);
    }

    unsigned long long win[7];
#pragma unroll
    for (int p = 0; p < 7; ++p) win[p] = 0ULL;

    auto insert_row = [&](int ry) {
        unsigned long long T = 0ULL;
        if (ry >= 0 && ry < IMG_H) {            // wave-uniform branch
            const float* rp = ip + ry * IMG_W;
            unsigned int qb[7];
#pragma unroll
            for (int dx = 0; dx < 7; ++dx) {
                float v = __ldg(rp + cc[dx]);
                // q = round(127 * clamp01((v+1)/2)) = floor(63.5v + 64) clamped
                float t = fmaf(v, 63.5f, 64.0f);
                t = fminf(fmaxf(t, 0.0f), 127.0f);
                t *= cm[dx];                    // out-of-range column -> 0
                qb[dx] = (unsigned int)t;       // 0..127
            }
            unsigned int lo = qb[0] | (qb[1] << 8) | (qb[2] << 16) | (qb[3] << 24);
            unsigned int hi = qb[4] | (qb[5] << 8) | (qb[6] << 16);
            T = ((unsigned long long)hi << 32) | (unsigned long long)lo;
            // 8x8 bit-matrix transpose (Hacker's Delight): byte dx (=q[dx])
            // -> byte p holds bit p of all 7 columns at bit dx.
            unsigned long long t2;
            t2 = (T ^ (T >> 7))  & 0x00AA00AA00AA00AAULL; T = T ^ t2 ^ (t2 << 7);
            t2 = (T ^ (T >> 14)) & 0x0000CCCC0000CCCCULL; T = T ^ t2 ^ (t2 << 14);
            t2 = (T ^ (T >> 28)) & 0x00000000F0F0F0F0ULL; T = T ^ t2 ^ (t2 << 28);
        }
#pragma unroll
        for (int p = 0; p < 7; ++p) {
            unsigned long long row = (T >> (8 * p)) & 0x7FULL;
            win[p] = (win[p] >> 7) | (row << 42);
        }
    };

    // Prologue: rows y0-3 .. y0+2
#pragma unroll
    for (int j = 0; j < 6; ++j) insert_row(y0 - 3 + j);

    for (int r = 0; r < RROWS; ++r) {
        const int y = y0 + r;
        insert_row(y + 3);                      // window now rows y-3..y+3

        // MSB-first radix select: rank 24 (0-indexed) of the 49 window bits
        unsigned long long act = 0x0001FFFFFFFFFFFFULL;  // 49 ones
        int cnt = 49, rank = 24;
        unsigned int m = 0;
#pragma unroll
        for (int p = 6; p >= 0; --p) {
            unsigned long long ones = act & win[p];
            int c1 = __popcll(ones);
            int c0 = cnt - c1;
            bool b = (rank >= c0);              // median has bit p set
            act  = b ? ones : (act ^ ones);     // act^ones == act & ~win[p]
            cnt  = b ? c1 : c0;
            rank = b ? (rank - c0) : rank;
            m    = (m << 1) | (b ? 1u : 0u);
        }
        // dequant: 2*(m/127) - 1, already in [-1,1]
        op[y * IMG_W + x] = fmaf((float)m, 2.0f / 127.0f, -1.0f);
    }
}

extern "C" void kernel_launch(void* const* d_in, const int* in_sizes, int n_in,
                              void* d_out, int out_size, void* d_ws, size_t ws_size,
                              hipStream_t stream) {
    const float* img = (const float*)d_in[0];   // image; cover_image unused
    float* out = (float*)d_out;
    const int planes = in_sizes[0] / (IMG_H * IMG_W);   // 16*3 = 48
    dim3 grid(planes * RUNS);
    dim3 block(256);
    median7_kernel<<<grid, block, 0, stream>>>(img, out);
}

// Round 2
// 25.097 us; speedup vs baseline: 1.0640x; 1.0640x over previous
//
#include <hip/hip_runtime.h>

// 7x7 median blur, zero padding, on (image+1)/2, then *2-1, clip [-1,1].
// Clamp to [0,1] commutes with median+clip; quantize to 7 bits round-to-nearest
// (error bound 1/127 = 7.9e-3 << 2e-2); rolling 49-bit bit-plane masks per
// thread down a column run; MSB-first radix select of rank 24 via popcount.
// R2: RROWS=8 (24 waves/CU), double-buffered pipelined loads, byte colmask,
// round-to-nearest, nontemporal stores.

#define IMG_H 256
#define IMG_W 256
#define RROWS 8                  // output rows per thread run
#define RUNS  (IMG_H / RROWS)    // 32

__global__ __launch_bounds__(256, 6)
void median7_kernel(const float* __restrict__ img, float* __restrict__ out) {
    const int x     = threadIdx.x;              // column 0..255
    const int plane = blockIdx.x / RUNS;        // b*c plane
    const int run   = blockIdx.x % RUNS;
    const int y0    = run * RROWS;

    const float* ip = img + (size_t)plane * (IMG_H * IMG_W);
    float*       op = out + (size_t)plane * (IMG_H * IMG_W);

    // Per-column tap addresses (clamped) + 64-bit byte validity mask.
    int cc[7];
    unsigned long long colmask = 0ULL;
#pragma unroll
    for (int dx = 0; dx < 7; ++dx) {
        int col = x + dx - 3;
        if (col >= 0 && col < IMG_W) colmask |= 0xFFULL << (8 * dx);
        cc[dx] = min(max(col, 0), IMG_W - 1);
    }

    unsigned long long win[7];
#pragma unroll
    for (int p = 0; p < 7; ++p) win[p] = 0ULL;

    auto load_row = [&](int ry, float* v) {
        int rc = min(max(ry, 0), IMG_H - 1);    // clamped address; masked later
        const float* rp = ip + rc * IMG_W;
#pragma unroll
        for (int dx = 0; dx < 7; ++dx) v[dx] = rp[cc[dx]];
    };

    auto insert_row = [&](const float* v, bool rowok) {
        unsigned int qb[7];
#pragma unroll
        for (int dx = 0; dx < 7; ++dx) {
            // q = round(127 * clamp01((v+1)/2)) = floor(63.5v + 64.5) clamped
            float t = fmaf(v[dx], 63.5f, 64.5f);
            t = fminf(fmaxf(t, 0.0f), 127.0f);  // v_med3_f32
            qb[dx] = (unsigned int)t;           // 0..127
        }
        unsigned int lo = qb[0] | (qb[1] << 8) | (qb[2] << 16) | (qb[3] << 24);
        unsigned int hi = qb[4] | (qb[5] << 8) | (qb[6] << 16);
        unsigned long long T = ((unsigned long long)hi << 32) | (unsigned long long)lo;
        T &= colmask;                            // zero-pad invalid columns
        T = rowok ? T : 0ULL;                    // zero-pad invalid rows (uniform)
        // 8x8 bit-matrix transpose (Hacker's Delight): byte dx -> byte p holds
        // bit p of all 7 columns.
        unsigned long long t2;
        t2 = (T ^ (T >> 7))  & 0x00AA00AA00AA00AAULL; T = T ^ t2 ^ (t2 << 7);
        t2 = (T ^ (T >> 14)) & 0x0000CCCC0000CCCCULL; T = T ^ t2 ^ (t2 << 14);
        t2 = (T ^ (T >> 28)) & 0x00000000F0F0F0F0ULL; T = T ^ t2 ^ (t2 << 28);
#pragma unroll
        for (int p = 0; p < 7; ++p) {
            unsigned long long row = (T >> (8 * p)) & 0x7FULL;
            win[p] = (win[p] >> 7) | (row << 42);
        }
    };

    auto select_store = [&](int y) {
        // MSB-first radix select: rank 24 (0-indexed) of the 49 window bits
        unsigned long long act = 0x0001FFFFFFFFFFFFULL;  // 49 ones
        int cnt = 49, rank = 24;
        unsigned int m = 0;
#pragma unroll
        for (int p = 6; p >= 0; --p) {
            unsigned long long ones = act & win[p];
            int c1 = __popcll(ones);
            int c0 = cnt - c1;
            bool b = (rank >= c0);              // median has bit p set
            act  = b ? ones : (act ^ ones);     // act^ones == act & ~win[p]
            cnt  = b ? c1 : c0;
            rank = b ? (rank - c0) : rank;
            m    = (m << 1) | (b ? 1u : 0u);
        }
        // dequant: 2*(m/127) - 1, already in [-1,1]
        __builtin_nontemporal_store(fmaf((float)m, 2.0f / 127.0f, -1.0f),
                                    &op[y * IMG_W + x]);
    };

    // Prologue: insert rows y0-3 .. y0+2, leave A = row y0+3 loaded.
    float A[7], B[7];
    load_row(y0 - 3, A);
    load_row(y0 - 2, B);
    insert_row(A, (y0 - 3) >= 0);
    load_row(y0 - 1, A);
    insert_row(B, (y0 - 2) >= 0);
    load_row(y0 + 0, B);
    insert_row(A, (y0 - 1) >= 0);
    load_row(y0 + 1, A);
    insert_row(B, true);
    load_row(y0 + 2, B);
    insert_row(A, true);
    load_row(y0 + 3, A);
    insert_row(B, true);

    // Main loop: 2 rows per step, statically alternating A/B buffers so the
    // next row's loads are in flight during insert+select of the current row.
#pragma unroll
    for (int r = 0; r < RROWS; r += 2) {
        load_row(y0 + r + 4, B);
        insert_row(A, (y0 + r + 3) < IMG_H);    // window now rows <= y0+r+3
        select_store(y0 + r);
        load_row(y0 + r + 5, A);                // last iter: harmless clamped load
        insert_row(B, (y0 + r + 4) < IMG_H);
        select_store(y0 + r + 1);
    }
}

extern "C" void kernel_launch(void* const* d_in, const int* in_sizes, int n_in,
                              void* d_out, int out_size, void* d_ws, size_t ws_size,
                              hipStream_t stream) {
    const float* img = (const float*)d_in[0];   // image; cover_image unused
    float* out = (float*)d_out;
    const int planes = in_sizes[0] / (IMG_H * IMG_W);   // 16*3 = 48
    dim3 grid(planes * RUNS);
    dim3 block(256);
    median7_kernel<<<grid, block, 0, stream>>>(img, out);
}

// Round 3
// 21.901 us; speedup vs baseline: 1.2193x; 1.1459x over previous
//
#include <hip/hip_runtime.h>
#include <stdint.h>

// 7x7 median blur, zero padding, on (image+1)/2, then *2-1, clip [-1,1].
// clamp01 commutes with median+clip; 8-bit round-to-nearest quantization
// (bound 1/255 = 3.9e-3 << 2e-2). Each lane keeps its OWN column's vertical
// bit-planes in one u64 V (byte p = 7-bit vertical mask of plane p), rolled
// per row via carry-free nibble-spread multiply. Per output row: share V via
// LDS (guard slots = 0 handle column padding for free), read 7 neighbors,
// 8x8 BYTE transpose via v_perm_b32 -> packed plane masks, popcount radix
// select of rank 24/49.

#define IMG_H 256
#define IMG_W 256
#define RROWS 8                  // output rows per thread run
#define RUNS  (IMG_H / RROWS)    // 32

#define PERM(a, b, s) __builtin_amdgcn_perm((a), (b), (s))

// Transpose half: 7 source u32 (byte p = plane pb+p vertical mask of col dx)
// -> 4 plane-mask u64s (P*lo byte dx = col dx of that plane, dx=0..3;
// P*hi = cols 4..6, byte 3 = 0).
// v_perm sel byte: 0..3 -> second operand's bytes, 4..7 -> first operand's.
#define TRHALF(S0_,S1_,S2_,S3_,S4_,S5_,S6_, A0,B0,A1,B1,A2,B2,A3,B3) do { \
    uint32_t za1 = PERM(S1_, S0_, 0x05010400u); /* (S0.b0,S1.b0,S0.b1,S1.b1) */ \
    uint32_t zb1 = PERM(S1_, S0_, 0x07030602u); \
    uint32_t za2 = PERM(S3_, S2_, 0x05010400u); \
    uint32_t zb2 = PERM(S3_, S2_, 0x07030602u); \
    uint32_t za3 = PERM(S5_, S4_, 0x05010400u); \
    uint32_t zb3 = PERM(S5_, S4_, 0x07030602u); \
    uint32_t za4 = PERM(0u,  S6_, 0x05010400u); /* (S6.b0,0,S6.b1,0) */       \
    uint32_t zb4 = PERM(0u,  S6_, 0x07030602u); \
    A0 = PERM(za2, za1, 0x05040100u);  B0 = PERM(za4, za3, 0x05040100u); \
    A1 = PERM(za2, za1, 0x07060302u);  B1 = PERM(za4, za3, 0x07060302u); \
    A2 = PERM(zb2, zb1, 0x05040100u);  B2 = PERM(zb4, zb3, 0x05040100u); \
    A3 = PERM(zb2, zb1, 0x07060302u);  B3 = PERM(zb4, zb3, 0x07060302u); \
} while (0)

// One radix-select round over the packed 49-bit window (7 cols x 7 bits,
// byte 7 and bit 7 of each byte always 0).
#define SELROUND(PLO, PHI) do { \
    uint32_t olo = aclo & (PLO), ohi = achi & (PHI); \
    int c1 = __popc(olo) + __popc(ohi); \
    int c0 = cnt - c1; \
    bool b = (rank >= c0); \
    aclo = b ? olo : (aclo ^ olo); \
    achi = b ? ohi : (achi ^ ohi); \
    cnt  = b ? c1 : c0; \
    rank = b ? (rank - c0) : rank; \
    med  = (med << 1) | (b ? 1u : 0u); \
} while (0)

__global__ __launch_bounds__(256, 6)
void median7_kernel(const float* __restrict__ img, float* __restrict__ out) {
    const int x     = threadIdx.x;            // column 0..255
    const int plane = blockIdx.x / RUNS;      // b*c plane
    const int run   = blockIdx.x % RUNS;
    const int y0    = run * RROWS;

    const float* ip = img + (size_t)plane * (IMG_H * IMG_W);
    float*       op = out + (size_t)plane * (IMG_H * IMG_W);

    // Double-buffered V exchange, 3 zero guard slots each side (= column pad).
    __shared__ unsigned long long VL[2][IMG_W + 6];
    if (x < 3) {
        VL[0][x] = 0ULL;             VL[1][x] = 0ULL;
        VL[0][IMG_W + 3 + x] = 0ULL; VL[1][IMG_W + 3 + x] = 0ULL;
    }

    // Own-column vertical planes: byte p bits 0..6 = plane p, rows old..new.
    uint32_t vlo = 0u, vhi = 0u;

    auto insert = [&](int ry) {
        int rc = min(max(ry, 0), IMG_H - 1);
        float v = ip[rc * IMG_W + x];
        // q = round(255 * clamp01((v+1)/2)) = floor(127.5 v + 128) clamped
        float t = fmaf(v, 127.5f, 128.0f);
        t = fminf(fmaxf(t, 0.0f), 255.0f);
        uint32_t q = (uint32_t)t;
        q = (ry >= 0 && ry < IMG_H) ? q : 0u;   // zero-pad rows
        // carry-free spread: bit p of nibble -> byte p, bit 6
        uint32_t nlo = ((q & 15u) * 0x08102040u) & 0x40404040u;
        uint32_t nhi = ((q >> 4)  * 0x08102040u) & 0x40404040u;
        vlo = ((vlo >> 1) & 0x3F3F3F3Fu) | nlo;
        vhi = ((vhi >> 1) & 0x3F3F3F3Fu) | nhi;
    };

    // Prologue: rows y0-3 .. y0+2
#pragma unroll
    for (int j = 0; j < 6; ++j) insert(y0 - 3 + j);

    for (int r = 0; r < RROWS; ++r) {
        insert(y0 + 3 + r);                   // window = rows y-3..y+3
        const int par = r & 1;
        VL[par][3 + x] = ((unsigned long long)vhi << 32) | vlo;
        __syncthreads();

        unsigned long long n0 = VL[par][x + 0];
        unsigned long long n1 = VL[par][x + 1];
        unsigned long long n2 = VL[par][x + 2];
        unsigned long long n3 = VL[par][x + 3];
        unsigned long long n4 = VL[par][x + 4];
        unsigned long long n5 = VL[par][x + 5];
        unsigned long long n6 = VL[par][x + 6];
        uint32_t L0 = (uint32_t)n0, H0 = (uint32_t)(n0 >> 32);
        uint32_t L1 = (uint32_t)n1, H1 = (uint32_t)(n1 >> 32);
        uint32_t L2 = (uint32_t)n2, H2 = (uint32_t)(n2 >> 32);
        uint32_t L3 = (uint32_t)n3, H3 = (uint32_t)(n3 >> 32);
        uint32_t L4 = (uint32_t)n4, H4 = (uint32_t)(n4 >> 32);
        uint32_t L5 = (uint32_t)n5, H5 = (uint32_t)(n5 >> 32);
        uint32_t L6 = (uint32_t)n6, H6 = (uint32_t)(n6 >> 32);

        // 8x8 byte transpose -> plane masks p0..p7 (u32 pairs)
        uint32_t p0lo,p0hi,p1lo,p1hi,p2lo,p2hi,p3lo,p3hi;
        uint32_t p4lo,p4hi,p5lo,p5hi,p6lo,p6hi,p7lo,p7hi;
        TRHALF(L0,L1,L2,L3,L4,L5,L6, p0lo,p0hi,p1lo,p1hi,p2lo,p2hi,p3lo,p3hi);
        TRHALF(H0,H1,H2,H3,H4,H5,H6, p4lo,p4hi,p5lo,p5hi,p6lo,p6hi,p7lo,p7hi);

        // MSB-first radix select, rank 24 of 49
        uint32_t aclo = 0x7F7F7F7Fu, achi = 0x007F7F7Fu;
        int cnt = 49, rank = 24;
        uint32_t med = 0u;
        SELROUND(p7lo, p7hi);
        SELROUND(p6lo, p6hi);
        SELROUND(p5lo, p5hi);
        SELROUND(p4lo, p4hi);
        SELROUND(p3lo, p3hi);
        SELROUND(p2lo, p2hi);
        SELROUND(p1lo, p1hi);
        SELROUND(p0lo, p0hi);

        // dequant: 2*med/255 - 1, already in [-1,1]
        __builtin_nontemporal_store(fmaf((float)med, 2.0f / 255.0f, -1.0f),
                                    &op[(y0 + r) * IMG_W + x]);
    }
}

extern "C" void kernel_launch(void* const* d_in, const int* in_sizes, int n_in,
                              void* d_out, int out_size, void* d_ws, size_t ws_size,
                              hipStream_t stream) {
    const float* img = (const float*)d_in[0];   // image; cover_image unused
    float* out = (float*)d_out;
    const int planes = in_sizes[0] / (IMG_H * IMG_W);   // 16*3 = 48
    dim3 grid(planes * RUNS);
    dim3 block(256);
    median7_kernel<<<grid, block, 0, stream>>>(img, out);
}